// Round 4
// baseline (224.740 us; speedup 1.0000x reference)
//
#include <hip/hip_runtime.h>
#include <cstdint>
#include <cstddef>

// ConcreteLayer forward: out = x @ softmax_rows((W + gumbel(U))/T)
// Reformulation v2 (dependency-broken):
//   e[i,k]   = exp((W+G)/T)          (stored bf16, UNSCALED, transposed -> BT [OUT,IN])
//   dpart[t,i] = partial row sums of e over OUT-tile t   (non-atomic, exclusive writes)
//   bt_scale:  BT[k,i] *= 1/sum_t dpart[t,i]             (16 MB pass)
//   out = bf16(x) @ BT                                   (256^2 8-phase MFMA GEMM, split-K=4)
// B=4096, IN=4096, OUT=1024.
// ws: xb (bf16 x, 32MB) | bt (bf16 e^T [OUT,IN], 8MB) | dpart ([16][4096] f32, 256KB)

#define TINYF 1.17549435082228750797e-38f
#define LN2F 0.69314718055994530942f
#define LOG2EF 1.44269504088896340736f

typedef unsigned short u16;
typedef __attribute__((ext_vector_type(8))) short bf16x8;
typedef __attribute__((ext_vector_type(4))) float f32x4;

__device__ __forceinline__ u16 f2bf(float f) {
  union { float f; uint32_t u; } v; v.f = f;
  uint32_t r = v.u + 0x7FFFu + ((v.u >> 16) & 1u);  // RNE
  return (u16)(r >> 16);
}
__device__ __forceinline__ float bf2f(u16 h) {
  union { float f; uint32_t u; } v; v.u = ((uint32_t)h) << 16;
  return v.f;
}

__device__ __forceinline__ float log2_hw(float x) { return __builtin_amdgcn_logf(x); }
__device__ __forceinline__ float exp2_hw(float x) { return __builtin_amdgcn_exp2f(x); }

// g = -ln(-ln(u)) = -ln2 * log2(ln2 * (-log2 u))
__device__ __forceinline__ float gumbel_fast(float u) {
  float t = -log2_hw(u);
  return -LN2F * log2_hw(t * LN2F);
}
__device__ __forceinline__ float exp_fast(float x) { return exp2_hw(x * LOG2EF); }

__device__ __forceinline__ void gld_lds16(const void* g, void* l) {
  __builtin_amdgcn_global_load_lds(
      (__attribute__((address_space(1))) void*)(g),
      (__attribute__((address_space(3))) void*)(l), 16, 0, 0);
}

// ---------------- kernel 1: fused prep ----------------
// blocks [0, 1024): 64x64 exp-transpose tiles of l -> BT (unscaled) + dpart sums
// blocks [1024, 1024+16384): x f32 -> bf16 cast (no scaling)
// blocks [1024+16384, +4096): zero out (split-K accumulator)
#define NB_TRANS 1024
#define NB_CAST 16384
#define NB_ZERO 4096

__global__ void prep_kernel(const float* __restrict__ W, const float* __restrict__ U,
                            const float* __restrict__ Tp, const float4* __restrict__ x,
                            u16* __restrict__ BT, float* __restrict__ dpart,
                            ushort4* __restrict__ xb, float4* __restrict__ out) {
  __shared__ float tile[64][65];
  const int bx = blockIdx.x;
  const int t = threadIdx.x;

  if (bx < NB_TRANS) {
    // ---- exp-transpose tile: k0 = IN-row tile (64 of them), n0 = OUT-col tile (16)
    const int k0 = (bx & 63) * 64, n0 = (bx >> 6) * 64;
    const float invT = 1.0f / Tp[0];
    {
      const int nn4 = (t & 15) * 4, kq = t >> 4;  // 16 rows per pass, float4 cols
#pragma unroll
      for (int r = 0; r < 4; ++r) {
        int kk = r * 16 + kq;
        size_t gi = (size_t)(k0 + kk) * 1024 + (n0 + nn4);
        float4 w = *(const float4*)&W[gi];
        float4 u = *(const float4*)&U[gi];
        float e0 = exp_fast((w.x + gumbel_fast(u.x * (1.0f - TINYF) + TINYF)) * invT);
        float e1 = exp_fast((w.y + gumbel_fast(u.y * (1.0f - TINYF) + TINYF)) * invT);
        float e2 = exp_fast((w.z + gumbel_fast(u.z * (1.0f - TINYF) + TINYF)) * invT);
        float e3 = exp_fast((w.w + gumbel_fast(u.w * (1.0f - TINYF) + TINYF)) * invT);
        tile[kk][nn4 + 0] = e0; tile[kk][nn4 + 1] = e1;
        tile[kk][nn4 + 2] = e2; tile[kk][nn4 + 3] = e3;
        // partial row sum over this thread's 4 cols; reduce across 16 lanes sharing kk
        float s = (e0 + e1) + (e2 + e3);
#pragma unroll
        for (int m = 8; m > 0; m >>= 1) s += __shfl_xor(s, m, 16);
        // exclusive (n-tile, row) slot: no atomics, no pre-zeroing needed
        if ((t & 15) == 0) dpart[(bx >> 6) * 4096 + k0 + kk] = s;
      }
    }
    __syncthreads();
    {
      const int kk4 = (t & 15) * 4, nq = t >> 4;
#pragma unroll
      for (int r = 0; r < 4; ++r) {
        int nn = r * 16 + nq;
        ushort4 o;
        o.x = f2bf(tile[kk4 + 0][nn]);
        o.y = f2bf(tile[kk4 + 1][nn]);
        o.z = f2bf(tile[kk4 + 2][nn]);
        o.w = f2bf(tile[kk4 + 3][nn]);
        *(ushort4*)&BT[(size_t)(n0 + nn) * 4096 + (k0 + kk4)] = o;
      }
    }
  } else if (bx < NB_TRANS + NB_CAST) {
    // ---- x f32 -> bf16 (unscaled; 1/d lives on the BT side)
    int i = (bx - NB_TRANS) * 256 + t;
    float4 v = x[i];
    ushort4 o;
    o.x = f2bf(v.x); o.y = f2bf(v.y); o.z = f2bf(v.z); o.w = f2bf(v.w);
    xb[i] = o;
  } else {
    // ---- zero split-K accumulator
    int j = (bx - NB_TRANS - NB_CAST) * 256 + t;
    out[j] = make_float4(0.f, 0.f, 0.f, 0.f);
  }
}

// ---------------- kernel 2: BT[k,i] *= 1/d_i ----------------
__global__ void bt_scale_kernel(u16* __restrict__ BT, const float* __restrict__ dpart) {
  __shared__ float invd[128];
  const int c0 = blockIdx.x * 128;  // IN col tile (32)
  const int r0 = blockIdx.y * 128;  // OUT row tile (8)
  const int t = threadIdx.x;
  if (t < 128) {
    float s = 0.f;
#pragma unroll
    for (int p = 0; p < 16; ++p) s += dpart[p * 4096 + c0 + t];
    invd[t] = 1.0f / s;
  }
  __syncthreads();
  const int cv = (t & 15) * 8, rq = t >> 4;
  const float4 ia = *(const float4*)&invd[cv];
  const float4 ib = *(const float4*)&invd[cv + 4];
#pragma unroll
  for (int pass = 0; pass < 8; ++pass) {
    int row = r0 + pass * 16 + rq;
    size_t gi = (size_t)row * 4096 + c0 + cv;
    ushort4 a = *(ushort4*)&BT[gi];
    ushort4 b = *(ushort4*)&BT[gi + 4];
    ushort4 oa, ob;
    oa.x = f2bf(bf2f(a.x) * ia.x); oa.y = f2bf(bf2f(a.y) * ia.y);
    oa.z = f2bf(bf2f(a.z) * ia.z); oa.w = f2bf(bf2f(a.w) * ia.w);
    ob.x = f2bf(bf2f(b.x) * ib.x); ob.y = f2bf(bf2f(b.y) * ib.y);
    ob.z = f2bf(bf2f(b.z) * ib.z); ob.w = f2bf(bf2f(b.w) * ib.w);
    *(ushort4*)&BT[gi] = oa;
    *(ushort4*)&BT[gi + 4] = ob;
  }
}

// ---------------- kernel 3: 256x256 8-phase GEMM, BK=64, split-K=4 ----------------
// 8 waves (2M x 4N), 512 threads, per-wave output 128x64. LDS 128KB dynamic:
// 2 dbuf x 4 half-tile slots (A-lo, A-hi, B-lo, B-hi; 16KB each).
// Per K-tile (BK=64): 4 phases, quadrant schedule (reads 12/4/8/0, 16 MFMA each).
// Stage cadence: exactly 1 half-tile per phase, 3-phase stage->use lead:
//   P1..P3: hts 1..3 of tile t1; P4: ht0 of t1+1; P5..P7: hts 1..3 of t1+1; P8: ht0 of t1+2.
// Buffer liveness: a tile's ds_reads all complete by its 3rd phase (each wave reads
// only its own A-half + B-half slots), so staging t+2 into the freed dbuf at P4-P7 is
// race-free. vmcnt(2) ONLY at phases 4/8 (the next tile's 4 half-tiles are the oldest
// outstanding; only the just-issued prefetch stays in flight) - never drain to 0 (T4).
// Tail: stage tile index clamps to NT-1 (same-data rewrite, benign; keeps vmcnt math).
// Swizzle: LDS granule p of row r holds global granule p^(r&7) (proven both-sides
// scheme from the 128^2 kernel): staging pre-swizzles the GLOBAL column, LDS stays
// lane-linear (gld_lds requirement); ds_read_b128 XORs the granule -> 2-way = free.
#define NT 16   // K-tiles per block: (4096/SPLITK)/64
#define NIT 8   // NT/2
#define SPLITK 4

__device__ __forceinline__ void stage_ht(const u16* __restrict__ Ak, const u16* __restrict__ Bk,
                                         int m0, int n0, char* smem, int tile, int ht,
                                         int w, int lane) {
  const u16* src = (ht < 2) ? (Ak + (size_t)(m0 + ht * 128) * 4096)
                            : (Bk + (size_t)(n0 + (ht - 2) * 128) * 4096);
  char* dst = smem + (tile & 1) * 65536 + ht * 16384;
  const int rr = lane >> 3;
  const int gcol = tile * 64 + (((lane & 7) ^ rr) << 3);
#pragma unroll
  for (int c = 0; c < 2; ++c) {
    const int chunk = w * 2 + c;  // 16 chunks x (8 rows x 64 cols) per half-tile
    gld_lds16(src + (size_t)(chunk * 8 + rr) * 4096 + gcol, dst + chunk * 1024);
  }
}

__launch_bounds__(512, 2)
__global__ void gemm_bt_kernel(const u16* __restrict__ A, const u16* __restrict__ BT,
                               float* __restrict__ C) {
  extern __shared__ char smem[];
  // bijective XCD-chunked swizzle (m204): 256 blocks = 8 XCD x 32
  int wg = blockIdx.x;
  wg = (wg & 7) * 32 + (wg >> 3);
  const int kz = wg >> 6;
  const int bx = wg & 15, by = (wg >> 4) & 3;
  const int m0 = bx * 256, n0 = by * 256;
  const int tid = threadIdx.x, lane = tid & 63, w = tid >> 6;
  const int wm = w >> 2, wn = w & 3;  // 2x4 wave grid; per-wave 128 rows x 64 cols
  const int r16 = lane & 15, quad = lane >> 4, r7 = r16 & 7;

  const u16* Ak = A + (size_t)kz * 1024;
  const u16* Bk = BT + (size_t)kz * 1024;

  // frag read bases: each wave touches only its A-half slot and B-half slot
  char* abase = smem + wm * 16384 + r16 * 128;
  char* bbase = smem + 32768 + (wn >> 1) * 16384 + ((wn & 1) * 64 + r16) * 128;
  const int gx[2] = {(quad ^ r7) * 16, ((4 + quad) ^ r7) * 16};  // granule: ss*4+quad

  bf16x8 aF[4][2], bF[4][2];
  f32x4 acc[8][4] = {};

#define RD_A(DB, MB)                                                              \
  _Pragma("unroll") for (int j = 0; j < 4; ++j) {                                 \
    aF[j][0] = *(const bf16x8*)(abase + (DB) * 65536 + ((MB) + j) * 2048 + gx[0]); \
    aF[j][1] = *(const bf16x8*)(abase + (DB) * 65536 + ((MB) + j) * 2048 + gx[1]); \
  }
#define RD_B(DB, NB)                                                                   \
  _Pragma("unroll") for (int j = 0; j < 2; ++j) {                                      \
    bF[(NB) + j][0] = *(const bf16x8*)(bbase + (DB) * 65536 + ((NB) + j) * 2048 + gx[0]); \
    bF[(NB) + j][1] = *(const bf16x8*)(bbase + (DB) * 65536 + ((NB) + j) * 2048 + gx[1]); \
  }
#define MM(MB, NB)                                                                \
  _Pragma("unroll") for (int mi = 0; mi < 4; ++mi)                                \
    _Pragma("unroll") for (int nj = 0; nj < 2; ++nj) {                            \
      acc[(MB) + mi][(NB) + nj] = __builtin_amdgcn_mfma_f32_16x16x32_bf16(        \
          aF[mi][0], bF[(NB) + nj][0], acc[(MB) + mi][(NB) + nj], 0, 0, 0);       \
      acc[(MB) + mi][(NB) + nj] = __builtin_amdgcn_mfma_f32_16x16x32_bf16(        \
          aF[mi][1], bF[(NB) + nj][1], acc[(MB) + mi][(NB) + nj], 0, 0, 0);       \
    }
#define PH(READS, STILE, SHT, MFMAS, BOUND)                                       \
  {                                                                               \
    READS                                                                         \
    {                                                                             \
      int tc = (STILE) < (NT - 1) ? (STILE) : (NT - 1);                           \
      stage_ht(Ak, Bk, m0, n0, smem, tc, (SHT), w, lane);                         \
    }                                                                             \
    __builtin_amdgcn_s_barrier();                                                 \
    asm volatile("s_waitcnt lgkmcnt(0)" ::: "memory");                            \
    __builtin_amdgcn_sched_barrier(0);                                            \
    __builtin_amdgcn_s_setprio(1);                                                \
    MFMAS                                                                         \
    __builtin_amdgcn_s_setprio(0);                                                \
    if (BOUND) asm volatile("s_waitcnt vmcnt(2)" ::: "memory");                   \
    __builtin_amdgcn_s_barrier();                                                 \
  }

  // prologue: tile0 fully + tile1 ht0; wait tile0 (2 newest stay in flight)
  stage_ht(Ak, Bk, m0, n0, smem, 0, 0, w, lane);
  stage_ht(Ak, Bk, m0, n0, smem, 0, 1, w, lane);
  stage_ht(Ak, Bk, m0, n0, smem, 0, 2, w, lane);
  stage_ht(Ak, Bk, m0, n0, smem, 0, 3, w, lane);
  stage_ht(Ak, Bk, m0, n0, smem, 1, 0, w, lane);
  asm volatile("s_waitcnt vmcnt(2)" ::: "memory");
  __builtin_amdgcn_s_barrier();

  for (int i = 0; i < NIT; ++i) {
    const int t1 = 2 * i + 1;
    PH(RD_A(0, 0) RD_B(0, 0), t1, 1, MM(0, 0), 0)
    PH(RD_B(0, 2),            t1, 2, MM(0, 2), 0)
    PH(RD_A(0, 4),            t1, 3, MM(4, 2), 0)
    PH({},                    t1 + 1, 0, MM(4, 0), 1)
    PH(RD_A(1, 0) RD_B(1, 0), t1 + 1, 1, MM(0, 0), 0)
    PH(RD_B(1, 2),            t1 + 1, 2, MM(0, 2), 0)
    PH(RD_A(1, 4),            t1 + 1, 3, MM(4, 2), 0)
    PH({},                    t1 + 2, 0, MM(4, 0), 1)
  }
#undef RD_A
#undef RD_B
#undef MM
#undef PH

  // epilogue: C/D layout col = lane&15, row = quad*4 + reg; split-K accumulate
#pragma unroll
  for (int mi = 0; mi < 8; ++mi)
#pragma unroll
    for (int ni = 0; ni < 4; ++ni)
#pragma unroll
      for (int r = 0; r < 4; ++r) {
        int row = m0 + wm * 128 + mi * 16 + quad * 4 + r;
        int col = n0 + wn * 64 + ni * 16 + r16;
        atomicAdd(&C[(size_t)row * 1024 + col], acc[mi][ni][r]);
      }
}

extern "C" void kernel_launch(void* const* d_in, const int* in_sizes, int n_in,
                              void* d_out, int out_size, void* d_ws, size_t ws_size,
                              hipStream_t stream) {
  const int M = 4096, K = 4096, N = 1024;  // B, IN, OUT
  const float* x = (const float*)d_in[0];
  const float* W = (const float*)d_in[1];
  const float* U = (const float*)d_in[2];
  const float* Tp = (const float*)d_in[3];
  float* out = (float*)d_out;

  char* ws = (char*)d_ws;
  u16* xb = (u16*)ws;                                          // 32 MB
  u16* bt = (u16*)(ws + (size_t)M * K * 2);                    // 8 MB
  float* dpart = (float*)(ws + (size_t)M * K * 2 + (size_t)N * K * 2);  // 256 KB

  static bool attr_done = false;
  if (!attr_done) {
    hipFuncSetAttribute((const void*)gemm_bt_kernel,
                        hipFuncAttributeMaxDynamicSharedMemorySize, 131072);
    attr_done = true;
  }

  prep_kernel<<<dim3(NB_TRANS + NB_CAST + NB_ZERO), 256, 0, stream>>>(
      W, U, Tp, (const float4*)x, bt, dpart, (ushort4*)xb, (float4*)out);
  bt_scale_kernel<<<dim3(32, 8), 256, 0, stream>>>(bt, dpart);
  gemm_bt_kernel<<<dim3(256), 512, 131072, stream>>>(xb, bt, out);
}